// Round 2
// baseline (323.346 us; speedup 1.0000x reference)
//
#include <hip/hip_runtime.h>

#define BX 4
#define VX 4
#define NN 1000
#define HEADS_ 4
#define OUTF 32
#define DM 128
#define EE 64000
#define NTOT 4000
#define ETOT 68000

// ---------------------------------------------------------------- h = x @ W^T
// x: (16000, 64) row-major; W: (128, 64) row-major; hbuf: (16000, 128)
__global__ __launch_bounds__(128) void h_kernel(const float* __restrict__ x,
                                                const float* __restrict__ W,
                                                float* __restrict__ hbuf) {
  int t = threadIdx.x;
  const float4* W4 = (const float4*)W;
  float4 w4[16];
#pragma unroll
  for (int j = 0; j < 16; ++j) w4[j] = W4[t * 16 + j];  // W row t in registers
  __shared__ float xs[128];
  int row0 = blockIdx.x * 32;  // 500 blocks x 32 rows
  for (int p = 0; p < 16; ++p) {
    int r = row0 + p * 2;
    __syncthreads();
    xs[t] = x[r * 64 + t];  // two consecutive rows, coalesced
    __syncthreads();
    float acc0 = 0.f, acc1 = 0.f;
#pragma unroll
    for (int j = 0; j < 16; ++j) {
      float4 w = w4[j];
      acc0 += xs[4*j+0]*w.x + xs[4*j+1]*w.y + xs[4*j+2]*w.z + xs[4*j+3]*w.w;
      acc1 += xs[64+4*j+0]*w.x + xs[64+4*j+1]*w.y + xs[64+4*j+2]*w.z + xs[64+4*j+3]*w.w;
    }
    hbuf[r * 128 + t] = acc0;
    hbuf[(r + 1) * 128 + t] = acc1;
  }
}

// ------------------------------------------------- per-node score halves
__global__ void node_score_kernel(const float* __restrict__ hbuf,
                                  const float* __restrict__ att,
                                  float* __restrict__ ssrc,
                                  float* __restrict__ sdst) {
  int j = blockIdx.x * blockDim.x + threadIdx.x;
  if (j >= NTOT) return;
  if (j < NN) {
#pragma unroll
    for (int h = 0; h < HEADS_; ++h) {
      float a0 = 0.f, a1 = 0.f;
#pragma unroll
      for (int k = 0; k < OUTF; ++k) {
        float g = hbuf[j * DM + h * OUTF + k];
        float lr = g > 0.f ? g : 0.2f * g;
        a0 += att[h * 64 + k] * lr;
        a1 += att[h * 64 + 32 + k] * lr;
      }
      ssrc[j * HEADS_ + h] = a0;
      sdst[j * HEADS_ + h] = a1;
    }
  } else {
#pragma unroll
    for (int h = 0; h < HEADS_; ++h) {
      ssrc[j * HEADS_ + h] = 0.f;
      sdst[j * HEADS_ + h] = 0.f;
    }
  }
}

// ------------------------ per-edge exp(score) + denom atomics + degree count
// denominator covers ALL edges (reference softmax over all dst segments);
// degree only counts "active" edges (src and dst in same graph block).
__global__ void edge_score_kernel(const int* __restrict__ ei,
                                  const float* __restrict__ ssrc,
                                  const float* __restrict__ sdst,
                                  float* __restrict__ exbuf,
                                  float* __restrict__ denom,
                                  int* __restrict__ deg) {
  int e = blockIdx.x * blockDim.x + threadIdx.x;
  if (e >= ETOT) return;
  int s, d;
  if (e < EE) { s = ei[e]; d = ei[EE + e]; }
  else { s = d = e - EE; }  // self loops
#pragma unroll
  for (int h = 0; h < HEADS_; ++h) {
    float sc = ssrc[s * HEADS_ + h] + sdst[d * HEADS_ + h];
    float ex = __expf(sc);  // shift-invariant; scores O(1), no max pass needed
    exbuf[e * HEADS_ + h] = ex;
    atomicAdd(&denom[d * HEADS_ + h], ex);
  }
  if (s / NN == d / NN) atomicAdd(&deg[d], 1);
}

// ------------------------------------------- exclusive scan of deg -> rowptr
__global__ __launch_bounds__(1024) void scan_kernel(const int* __restrict__ deg,
                                                    int* __restrict__ rowptr,
                                                    int* __restrict__ cursor) {
  __shared__ int part[1024];
  int t = threadIdx.x;
  int v[4];
  int s = 0;
#pragma unroll
  for (int q = 0; q < 4; ++q) {
    int idx = t * 4 + q;
    v[q] = (idx < NTOT) ? deg[idx] : 0;
    s += v[q];
  }
  part[t] = s;
  __syncthreads();
  for (int off = 1; off < 1024; off <<= 1) {
    int val = part[t];
    int add = (t >= off) ? part[t - off] : 0;
    __syncthreads();
    part[t] = val + add;
    __syncthreads();
  }
  int excl = (t > 0) ? part[t - 1] : 0;
#pragma unroll
  for (int q = 0; q < 4; ++q) {
    int idx = t * 4 + q;
    if (idx <= NTOT) rowptr[idx] = excl;
    if (idx < NTOT) cursor[idx] = excl;
    excl += v[q];
  }
}

// ------------------------------------------------------------- CSR fill
__global__ void fill_kernel(const int* __restrict__ ei,
                            int* __restrict__ cursor,
                            int2* __restrict__ elist) {
  int e = blockIdx.x * blockDim.x + threadIdx.x;
  if (e >= ETOT) return;
  int s, d;
  if (e < EE) { s = ei[e]; d = ei[EE + e]; }
  else { s = d = e - EE; }
  if (s / NN == d / NN) {
    int pos = atomicAdd(&cursor[d], 1);
    elist[pos] = make_int2(s, e);
  }
}

// ---------------------------------------- gather aggregation (no atomics)
// out[b,v,n,c] = sum_{e in CSR[n]} alpha[e,h(c)] * hbuf[(b*V+v)*NN + sl, c]
__global__ __launch_bounds__(128) void gather_kernel(const int* __restrict__ rowptr,
                                                     const int2* __restrict__ elist,
                                                     const float* __restrict__ exbuf,
                                                     const float* __restrict__ denom,
                                                     const float* __restrict__ hbuf,
                                                     float* __restrict__ out) {
  int d = blockIdx.x;          // global dst node id
  int t = threadIdx.x;
  int h = t >> 5;
  int b = d / NN, n = d - b * NN;
  float rd = 1.f / (denom[d * HEADS_ + h] + 1e-16f);
  float acc0 = 0.f, acc1 = 0.f, acc2 = 0.f, acc3 = 0.f;
  int beg = rowptr[d], end = rowptr[d + 1];
  for (int idx = beg; idx < end; ++idx) {
    int2 se = elist[idx];
    float alpha = exbuf[se.y * HEADS_ + h] * rd;
    int sl = se.x - b * NN;
    const float* hrow = hbuf + ((size_t)(b * VX) * NN + sl) * DM;
    acc0 += alpha * hrow[t];
    acc1 += alpha * hrow[NN * DM + t];
    acc2 += alpha * hrow[2 * NN * DM + t];
    acc3 += alpha * hrow[3 * NN * DM + t];
  }
  size_t o = ((size_t)(b * VX) * NN + n) * DM + t;
  out[o] = acc0;
  out[o + NN * DM] = acc1;
  out[o + 2 * NN * DM] = acc2;
  out[o + 3 * NN * DM] = acc3;
}

// ------------------------------- qkv GEMM: weight-stationary in registers
// qkv[r][j] = dot(hgat_row(r), inw[j]) + inb[j];  r = node*4 + v, j in [0,384)
__global__ __launch_bounds__(384) void qkv_kernel(const float* __restrict__ hgat,
                                                  const float* __restrict__ inw,
                                                  const float* __restrict__ inb,
                                                  float* __restrict__ qkv) {
  int j = threadIdx.x;
  const float4* inw4 = (const float4*)inw;
  float4 w[32];
#pragma unroll
  for (int k4 = 0; k4 < 32; ++k4) w[k4] = inw4[j * 32 + k4];  // row j in VGPRs
  float bj = inb[j];
  int r0 = blockIdx.x * 32;  // 500 blocks x 32 rows
  for (int i = 0; i < 32; ++i) {
    int r = r0 + i;
    int b = r / 4000, rem = r - b * 4000;
    int v = rem & 3, n = rem >> 2;
    const float4* a4 = (const float4*)(hgat + ((size_t)((b * VX + v) * NN + n)) * DM);
    float acc0 = 0.f, acc1 = 0.f, acc2 = 0.f, acc3 = 0.f;
#pragma unroll
    for (int k4 = 0; k4 < 32; k4 += 4) {
      float4 a0 = a4[k4], a1 = a4[k4+1], a2 = a4[k4+2], a3 = a4[k4+3];
      acc0 += a0.x*w[k4].x + a0.y*w[k4].y + a0.z*w[k4].z + a0.w*w[k4].w;
      acc1 += a1.x*w[k4+1].x + a1.y*w[k4+1].y + a1.z*w[k4+1].z + a1.w*w[k4+1].w;
      acc2 += a2.x*w[k4+2].x + a2.y*w[k4+2].y + a2.z*w[k4+2].z + a2.w*w[k4+2].w;
      acc3 += a3.x*w[k4+3].x + a3.y*w[k4+3].y + a3.z*w[k4+3].z + a3.w*w[k4+3].w;
    }
    qkv[(size_t)r * 384 + j] = acc0 + acc1 + acc2 + acc3 + bj;
  }
}

// ------------------------------------------------ attention over V per node
__global__ __launch_bounds__(128) void attn_kernel(const float* __restrict__ qkv,
                                                   float* __restrict__ ao) {
  int node = blockIdx.x;
  int t = threadIdx.x;
  __shared__ float qs[VX][DM], ks[VX][DM], vs[VX][DM];
  __shared__ float aw[VX][HEADS_][VX];
#pragma unroll
  for (int v = 0; v < VX; ++v) {
    size_t base = (size_t)(node * 4 + v) * 384;
    qs[v][t] = qkv[base + t];
    ks[v][t] = qkv[base + 128 + t];
    vs[v][t] = qkv[base + 256 + t];
  }
  __syncthreads();
  if (t < 64) {  // (vq, vk, h) dot products, length 32
    int vq = t >> 4, vk = (t >> 2) & 3, h = t & 3;
    float acc = 0.f;
#pragma unroll
    for (int kd = 0; kd < 32; ++kd) acc += qs[vq][h * 32 + kd] * ks[vk][h * 32 + kd];
    aw[vq][h][vk] = acc * 0.17677669529663687f;  // 1/sqrt(32)
  }
  __syncthreads();
  if (t < 16) {  // softmax over vk per (vq, h)
    int vq = t >> 2, h = t & 3;
    float m = aw[vq][h][0];
    for (int i = 1; i < 4; ++i) m = fmaxf(m, aw[vq][h][i]);
    float e[4], s = 0.f;
    for (int i = 0; i < 4; ++i) { e[i] = __expf(aw[vq][h][i] - m); s += e[i]; }
    for (int i = 0; i < 4; ++i) aw[vq][h][i] = e[i] / s;
  }
  __syncthreads();
  int h = t >> 5;
#pragma unroll
  for (int vq = 0; vq < VX; ++vq) {
    float acc = 0.f;
#pragma unroll
    for (int vk = 0; vk < VX; ++vk) acc += aw[vq][h][vk] * vs[vk][t];
    ao[(size_t)(node * 4 + vq) * DM + t] = acc;
  }
}

// ------------------------- out_proj GEMM: weight-stationary in registers
__global__ __launch_bounds__(256) void outproj_kernel(const float* __restrict__ ao,
                                                      const float* __restrict__ outw,
                                                      const float* __restrict__ outb,
                                                      const float* __restrict__ bias,
                                                      float* __restrict__ out) {
  int j = threadIdx.x & 127, s = threadIdx.x >> 7;
  const float4* outw4 = (const float4*)outw;
  float4 w[32];
#pragma unroll
  for (int k4 = 0; k4 < 32; ++k4) w[k4] = outw4[j * 32 + k4];
  float base = outb[j] + bias[j];
  int r0 = blockIdx.x * 32;  // 500 blocks x 32 rows, 2 rows in flight per block
  for (int i = 0; i < 16; ++i) {
    int r = r0 + i * 2 + s;
    const float4* a4 = (const float4*)(ao + (size_t)r * DM);
    float acc0 = 0.f, acc1 = 0.f, acc2 = 0.f, acc3 = 0.f;
#pragma unroll
    for (int k4 = 0; k4 < 32; k4 += 4) {
      float4 a0 = a4[k4], a1 = a4[k4+1], a2 = a4[k4+2], a3 = a4[k4+3];
      acc0 += a0.x*w[k4].x + a0.y*w[k4].y + a0.z*w[k4].z + a0.w*w[k4].w;
      acc1 += a1.x*w[k4+1].x + a1.y*w[k4+1].y + a1.z*w[k4+1].z + a1.w*w[k4+1].w;
      acc2 += a2.x*w[k4+2].x + a2.y*w[k4+2].y + a2.z*w[k4+2].z + a2.w*w[k4+2].w;
      acc3 += a3.x*w[k4+3].x + a3.y*w[k4+3].y + a3.z*w[k4+3].z + a3.w*w[k4+3].w;
    }
    int b = r / 4000, rem = r - b * 4000;
    int v = rem & 3, n = rem >> 2;
    out[((size_t)((b * VX + v) * NN + n)) * DM + j] = acc0 + acc1 + acc2 + acc3 + base;
  }
}

extern "C" void kernel_launch(void* const* d_in, const int* in_sizes, int n_in,
                              void* d_out, int out_size, void* d_ws, size_t ws_size,
                              hipStream_t stream) {
  const float* x    = (const float*)d_in[0];
  const float* W    = (const float*)d_in[1];
  const float* att  = (const float*)d_in[2];
  const float* inw  = (const float*)d_in[3];
  const float* inb  = (const float*)d_in[4];
  const float* outw = (const float*)d_in[5];
  const float* outb = (const float*)d_in[6];
  const float* bias = (const float*)d_in[7];
  const int*   ei   = (const int*)d_in[8];
  float* out = (float*)d_out;

  float* ws = (float*)d_ws;
  // ---- early-phase layout (floats) ----
  float* hbuf   = ws;                        // 2,048,000
  float* ssrc   = hbuf + 2048000;            // 16,000
  float* sdst   = ssrc + 16000;              // 16,000
  float* denom  = sdst + 16000;              // 16,000
  int*   deg    = (int*)(denom + 16000);     // 4,000 (adjacent to denom: 1 memset)
  float* exbuf  = (float*)(deg + 4000);      // 272,000
  int*   rowptr = (int*)(exbuf + 272000);    // 4,001
  int*   cursor = rowptr + 4001;             // 4,000
  int2*  elist  = (int2*)(cursor + 4000);    // 68,000 int2
  // ---- late-phase layout (aliases early region; gather has completed) ----
  float* ao  = ws;             // 2,048,000 (aliases hbuf — dead after gather)
  float* qkv = ws + 2048000;   // 6,144,000 (aliases score/CSR region — dead after gather)
  // peak ws use: 8,192,000 floats = 32.8 MB

  hipMemsetAsync(denom, 0, 16000 * sizeof(float) + 4000 * sizeof(int), stream);

  h_kernel<<<500, 128, 0, stream>>>(x, W, hbuf);
  node_score_kernel<<<(NTOT + 255) / 256, 256, 0, stream>>>(hbuf, att, ssrc, sdst);
  edge_score_kernel<<<(ETOT + 255) / 256, 256, 0, stream>>>(ei, ssrc, sdst, exbuf, denom, deg);
  scan_kernel<<<1, 1024, 0, stream>>>(deg, rowptr, cursor);
  fill_kernel<<<(ETOT + 255) / 256, 256, 0, stream>>>(ei, cursor, elist);
  gather_kernel<<<NTOT, 128, 0, stream>>>(rowptr, elist, exbuf, denom, hbuf, out);
  qkv_kernel<<<500, 384, 0, stream>>>(out, inw, inb, qkv);
  attn_kernel<<<NTOT, 128, 0, stream>>>(qkv, ao);
  outproj_kernel<<<500, 256, 0, stream>>>(ao, outw, outb, bias, out);
}

// Round 3
// 174.726 us; speedup vs baseline: 1.8506x; 1.8506x over previous
//
#include <hip/hip_runtime.h>

#define BX 4
#define VX 4
#define NN 1000
#define HEADS_ 4
#define OUTF 32
#define DM 128
#define EE 64000
#define NTOT 4000
#define ETOT 68000

// ---------------------------------------------------------------------------
// Tiled GEMM: C[M][N] = A[M][K] @ Wt[N][K]^T (+ b1[n] + b2[n])
// 64x64 tile, 256 threads, 4x4 micro-tile, full K staged in LDS.
// LDS is K-major with XOR-swizzled 4-float column groups:
//   phys_group(k, c) = (c/4) ^ ((k/4) & 15)   (64 cols = 16 groups, exact perm)
// -> staging transpose-writes are <=4-way conflicted; frag reads are aligned
//    ds_read_b128, 16-fold broadcast, conflict-free.
// ---------------------------------------------------------------------------
template <int K>
__global__ __launch_bounds__(256) void gemm_kernel(const float* __restrict__ A,
                                                   const float* __restrict__ Wt,
                                                   const float* __restrict__ b1,
                                                   const float* __restrict__ b2,
                                                   float* __restrict__ C,
                                                   int N) {
  constexpr int KQ = K / 4;
  __shared__ float As[K * 64];
  __shared__ float Bs[K * 64];
  int tid = threadIdx.x;
  int m0 = blockIdx.x * 64, n0 = blockIdx.y * 64;

  {  // stage + transpose + swizzle (A rows m0.., Wt rows n0..)
    int k4 = tid % KQ;
    constexpr int RSTEP = 256 / KQ;  // rows per pass: K=128 -> 8, K=64 -> 16
    for (int mr = tid / KQ; mr < 64; mr += RSTEP) {
      float4 av = ((const float4*)(A + (size_t)(m0 + mr) * K))[k4];
      float4 bv = ((const float4*)(Wt + (size_t)(n0 + mr) * K))[k4];
      int g = (mr >> 2) ^ (k4 & 15);
      int base = (k4 * 4) * 64 + g * 4 + (mr & 3);
      As[base] = av.x; As[base + 64] = av.y; As[base + 128] = av.z; As[base + 192] = av.w;
      Bs[base] = bv.x; Bs[base + 64] = bv.y; Bs[base + 128] = bv.z; Bs[base + 192] = bv.w;
    }
  }
  __syncthreads();

  int tx = tid & 15;                              // n-group
  int ty = ((tid >> 6) << 2) | ((tid >> 4) & 3);  // m-group (wave-local 4 -> broadcast)
  const float4* As4 = (const float4*)As;          // [K][16]
  const float4* Bs4 = (const float4*)Bs;
  float acc[4][4] = {};
  for (int kq = 0; kq < KQ; ++kq) {
    int ga = ty ^ (kq & 15);
    int gb = tx ^ (kq & 15);
#pragma unroll
    for (int j = 0; j < 4; ++j) {
      float4 a = As4[(kq * 4 + j) * 16 + ga];
      float4 b = Bs4[(kq * 4 + j) * 16 + gb];
      float av4[4] = {a.x, a.y, a.z, a.w};
      float bv4[4] = {b.x, b.y, b.z, b.w};
#pragma unroll
      for (int i = 0; i < 4; ++i)
#pragma unroll
        for (int jj = 0; jj < 4; ++jj) acc[i][jj] += av4[i] * bv4[jj];
    }
  }

  float badd[4] = {0.f, 0.f, 0.f, 0.f};
  int nc = n0 + tx * 4;
  if (b1) { badd[0] = b1[nc]; badd[1] = b1[nc+1]; badd[2] = b1[nc+2]; badd[3] = b1[nc+3]; }
  if (b2) { badd[0] += b2[nc]; badd[1] += b2[nc+1]; badd[2] += b2[nc+2]; badd[3] += b2[nc+3]; }
#pragma unroll
  for (int i = 0; i < 4; ++i) {
    int m = m0 + ty * 4 + i;
    float4 o = make_float4(acc[i][0] + badd[0], acc[i][1] + badd[1],
                           acc[i][2] + badd[2], acc[i][3] + badd[3]);
    ((float4*)(C + (size_t)m * N + n0))[tx] = o;
  }
}

// ------------------------------------------------- per-node score halves
__global__ void node_score_kernel(const float* __restrict__ hbuf,
                                  const float* __restrict__ att,
                                  float* __restrict__ ssrc,
                                  float* __restrict__ sdst) {
  int j = blockIdx.x * blockDim.x + threadIdx.x;
  if (j >= NTOT) return;
  if (j < NN) {
#pragma unroll
    for (int h = 0; h < HEADS_; ++h) {
      float a0 = 0.f, a1 = 0.f;
#pragma unroll
      for (int k = 0; k < OUTF; ++k) {
        float g = hbuf[j * DM + h * OUTF + k];
        float lr = g > 0.f ? g : 0.2f * g;
        a0 += att[h * 64 + k] * lr;
        a1 += att[h * 64 + 32 + k] * lr;
      }
      ssrc[j * HEADS_ + h] = a0;
      sdst[j * HEADS_ + h] = a1;
    }
  } else {
#pragma unroll
    for (int h = 0; h < HEADS_; ++h) {
      ssrc[j * HEADS_ + h] = 0.f;
      sdst[j * HEADS_ + h] = 0.f;
    }
  }
}

// ------------------------ per-edge exp(score) + denom atomics + degree count
__global__ void edge_score_kernel(const int* __restrict__ ei,
                                  const float* __restrict__ ssrc,
                                  const float* __restrict__ sdst,
                                  float* __restrict__ exbuf,
                                  float* __restrict__ denom,
                                  int* __restrict__ deg) {
  int e = blockIdx.x * blockDim.x + threadIdx.x;
  if (e >= ETOT) return;
  int s, d;
  if (e < EE) { s = ei[e]; d = ei[EE + e]; }
  else { s = d = e - EE; }  // self loops
#pragma unroll
  for (int h = 0; h < HEADS_; ++h) {
    float sc = ssrc[s * HEADS_ + h] + sdst[d * HEADS_ + h];
    float ex = __expf(sc);  // shift-invariant; scores O(1), no max pass needed
    exbuf[e * HEADS_ + h] = ex;
    atomicAdd(&denom[d * HEADS_ + h], ex);
  }
  if (s / NN == d / NN) atomicAdd(&deg[d], 1);
}

// ------------------------------------------- exclusive scan of deg -> rowptr
__global__ __launch_bounds__(1024) void scan_kernel(const int* __restrict__ deg,
                                                    int* __restrict__ rowptr,
                                                    int* __restrict__ cursor) {
  __shared__ int part[1024];
  int t = threadIdx.x;
  int v[4];
  int s = 0;
#pragma unroll
  for (int q = 0; q < 4; ++q) {
    int idx = t * 4 + q;
    v[q] = (idx < NTOT) ? deg[idx] : 0;
    s += v[q];
  }
  part[t] = s;
  __syncthreads();
  for (int off = 1; off < 1024; off <<= 1) {
    int val = part[t];
    int add = (t >= off) ? part[t - off] : 0;
    __syncthreads();
    part[t] = val + add;
    __syncthreads();
  }
  int excl = (t > 0) ? part[t - 1] : 0;
#pragma unroll
  for (int q = 0; q < 4; ++q) {
    int idx = t * 4 + q;
    if (idx <= NTOT) rowptr[idx] = excl;
    if (idx < NTOT) cursor[idx] = excl;
    excl += v[q];
  }
}

// ------------------------------------------------------------- CSR fill
__global__ void fill_kernel(const int* __restrict__ ei,
                            int* __restrict__ cursor,
                            int2* __restrict__ elist) {
  int e = blockIdx.x * blockDim.x + threadIdx.x;
  if (e >= ETOT) return;
  int s, d;
  if (e < EE) { s = ei[e]; d = ei[EE + e]; }
  else { s = d = e - EE; }
  if (s / NN == d / NN) {
    int pos = atomicAdd(&cursor[d], 1);
    elist[pos] = make_int2(s, e);
  }
}

// ---------------------------------------- gather aggregation (no atomics)
__global__ __launch_bounds__(128) void gather_kernel(const int* __restrict__ rowptr,
                                                     const int2* __restrict__ elist,
                                                     const float* __restrict__ exbuf,
                                                     const float* __restrict__ denom,
                                                     const float* __restrict__ hbuf,
                                                     float* __restrict__ out) {
  int d = blockIdx.x;  // global dst node id
  int t = threadIdx.x;
  int h = t >> 5;
  int b = d / NN, n = d - b * NN;
  float rd = 1.f / (denom[d * HEADS_ + h] + 1e-16f);
  float acc0 = 0.f, acc1 = 0.f, acc2 = 0.f, acc3 = 0.f;
  int beg = rowptr[d], end = rowptr[d + 1];
  for (int idx = beg; idx < end; ++idx) {
    int2 se = elist[idx];
    float alpha = exbuf[se.y * HEADS_ + h] * rd;
    int sl = se.x - b * NN;
    const float* hrow = hbuf + ((size_t)(b * VX) * NN + sl) * DM;
    acc0 += alpha * hrow[t];
    acc1 += alpha * hrow[NN * DM + t];
    acc2 += alpha * hrow[2 * NN * DM + t];
    acc3 += alpha * hrow[3 * NN * DM + t];
  }
  size_t o = ((size_t)(b * VX) * NN + n) * DM + t;
  out[o] = acc0;
  out[o + NN * DM] = acc1;
  out[o + 2 * NN * DM] = acc2;
  out[o + 3 * NN * DM] = acc3;
}

// ------------------------------------------- attention over V, 2 nodes/block
// row order everywhere: r = (b*4+v)*1000 + n
__global__ __launch_bounds__(256) void attn_kernel(const float* __restrict__ qkv,
                                                   float* __restrict__ ao) {
  int li = threadIdx.x >> 7;  // node-in-block
  int t = threadIdx.x & 127;
  int node = blockIdx.x * 2 + li;  // 0..3999
  int b = node / NN, n = node - b * NN;
  __shared__ float qs[2][VX][DM], ks[2][VX][DM], vs[2][VX][DM];
  __shared__ float aw[2][VX][HEADS_][VX];
#pragma unroll
  for (int v = 0; v < VX; ++v) {
    size_t base = (size_t)((b * VX + v) * NN + n) * 384;
    qs[li][v][t] = qkv[base + t];
    ks[li][v][t] = qkv[base + 128 + t];
    vs[li][v][t] = qkv[base + 256 + t];
  }
  __syncthreads();
  if (t < 64) {  // (vq, vk, h) dot products, length 32
    int vq = t >> 4, vk = (t >> 2) & 3, h = t & 3;
    float acc = 0.f;
#pragma unroll
    for (int kd = 0; kd < 32; ++kd)
      acc += qs[li][vq][h * 32 + kd] * ks[li][vk][h * 32 + kd];
    aw[li][vq][h][vk] = acc * 0.17677669529663687f;  // 1/sqrt(32)
  }
  __syncthreads();
  if (t < 16) {  // softmax over vk per (vq, h)
    int vq = t >> 2, h = t & 3;
    float m = aw[li][vq][h][0];
    for (int i = 1; i < 4; ++i) m = fmaxf(m, aw[li][vq][h][i]);
    float e[4], s = 0.f;
    for (int i = 0; i < 4; ++i) { e[i] = __expf(aw[li][vq][h][i] - m); s += e[i]; }
    for (int i = 0; i < 4; ++i) aw[li][vq][h][i] = e[i] / s;
  }
  __syncthreads();
  int h = t >> 5;
#pragma unroll
  for (int vq = 0; vq < VX; ++vq) {
    float acc = 0.f;
#pragma unroll
    for (int vk = 0; vk < VX; ++vk) acc += aw[li][vq][h][vk] * vs[li][vk][t];
    ao[(size_t)((b * VX + vq) * NN + n) * DM + t] = acc;
  }
}

extern "C" void kernel_launch(void* const* d_in, const int* in_sizes, int n_in,
                              void* d_out, int out_size, void* d_ws, size_t ws_size,
                              hipStream_t stream) {
  const float* x    = (const float*)d_in[0];
  const float* W    = (const float*)d_in[1];
  const float* att  = (const float*)d_in[2];
  const float* inw  = (const float*)d_in[3];
  const float* inb  = (const float*)d_in[4];
  const float* outw = (const float*)d_in[5];
  const float* outb = (const float*)d_in[6];
  const float* bias = (const float*)d_in[7];
  const int*   ei   = (const int*)d_in[8];
  float* out = (float*)d_out;

  float* ws = (float*)d_ws;
  // ---- early-phase layout (floats) ----
  float* hbuf   = ws;                      // 2,048,000
  float* ssrc   = hbuf + 2048000;          // 16,000
  float* sdst   = ssrc + 16000;            // 16,000
  float* denom  = sdst + 16000;            // 16,000
  int*   deg    = (int*)(denom + 16000);   // 4,000 (adjacent: one memset)
  float* exbuf  = (float*)(deg + 4000);    // 272,000
  int*   rowptr = (int*)(exbuf + 272000);  // 4,001
  int*   cursor = rowptr + 4001;           // 4,000
  int2*  elist  = (int2*)(cursor + 4000);  // 68,000 int2
  // ---- late-phase layout (aliases early region; gather has completed) ----
  float* ao  = ws;            // aliases hbuf (dead after gather)
  float* qkv = ws + 2048000;  // 6,144,000 (aliases score/CSR region)

  hipMemsetAsync(denom, 0, 16000 * sizeof(float) + 4000 * sizeof(int), stream);

  // h = x @ W^T : M=16000, K=64, N=128
  gemm_kernel<64><<<dim3(250, 2), 256, 0, stream>>>(x, W, nullptr, nullptr, hbuf, 128);
  node_score_kernel<<<(NTOT + 255) / 256, 256, 0, stream>>>(hbuf, att, ssrc, sdst);
  edge_score_kernel<<<(ETOT + 255) / 256, 256, 0, stream>>>(ei, ssrc, sdst, exbuf, denom, deg);
  scan_kernel<<<1, 1024, 0, stream>>>(deg, rowptr, cursor);
  fill_kernel<<<(ETOT + 255) / 256, 256, 0, stream>>>(ei, cursor, elist);
  gather_kernel<<<NTOT, 128, 0, stream>>>(rowptr, elist, exbuf, denom, hbuf, out);
  // qkv = hgat @ inw^T + inb : M=16000, K=128, N=384
  gemm_kernel<128><<<dim3(250, 6), 256, 0, stream>>>(out, inw, inb, nullptr, qkv, 384);
  attn_kernel<<<2000, 256, 0, stream>>>(qkv, ao);
  // out = ao @ outw^T + outb + bias : M=16000, K=128, N=128
  gemm_kernel<128><<<dim3(250, 2), 256, 0, stream>>>(ao, outw, outb, bias, out, 128);
}